// Round 1
// baseline (1629.673 us; speedup 1.0000x reference)
//
#include <hip/hip_runtime.h>
#include <hip/hip_bf16.h>

#define N_NODES 100000
#define E_EDGES 1600000
#define DIN 128
#define DH 64
#define DOUT 40
#define LN_EPS 1e-5f

// ---------------------------------------------------------------- degree
__global__ void deg_count_k(const int* __restrict__ dst, float* __restrict__ deg) {
    int e = blockIdx.x * blockDim.x + threadIdx.x;
    if (e < E_EDGES) atomicAdd(&deg[dst[e]], 1.0f);
}

__global__ void dinv_k(float* __restrict__ deg) {
    int n = blockIdx.x * blockDim.x + threadIdx.x;
    if (n < N_NODES) deg[n] = rsqrtf(deg[n] + 1.0f);  // A + I self loop
}

// ---------------------------------------------------------------- GEMM  [N,K] @ [K,64] -> [N,64]
// block = 256 threads = 4 waves, one node per wave, lane = output feature.
template <int K>
__global__ void gemm_nk64(const float* __restrict__ X, const float* __restrict__ W,
                          float* __restrict__ H) {
    __shared__ float sW[K * 64];
    __shared__ float sX[4 * K];
    int tid = threadIdx.x;
    for (int i = tid; i < K * 64; i += 256) sW[i] = W[i];
    int nodeBase = blockIdx.x * 4;
    for (int i = tid; i < 4 * K; i += 256) {
        int node = nodeBase + i / K;
        sX[i] = (node < N_NODES) ? X[(long)node * K + (i % K)] : 0.f;
    }
    __syncthreads();
    int w = tid >> 6, lane = tid & 63;
    int node = nodeBase + w;
    if (node >= N_NODES) return;
    const float* xr = &sX[w * K];
    float acc = 0.f;
#pragma unroll 8
    for (int k = 0; k < K; ++k) acc = fmaf(xr[k], sW[k * 64 + lane], acc);
    H[(long)node * 64 + lane] = acc;
}

// ---------------------------------------------------------------- edge scatter
// one wave per edge; lane = feature. agg[dst] += h[src] * dinv[src]*dinv[dst]
__global__ void scatter_k(const int* __restrict__ src, const int* __restrict__ dst,
                          const float* __restrict__ dinv, const float* __restrict__ H,
                          float* __restrict__ AGG) {
    long gid = (long)blockIdx.x * blockDim.x + threadIdx.x;
    int e = (int)(gid >> 6);
    int lane = (int)(gid & 63);
    if (e >= E_EDGES) return;
    int s = src[e], d = dst[e];
    float w = dinv[s] * dinv[d];
    atomicAdd(&AGG[(long)d * 64 + lane], H[(long)s * 64 + lane] * w);
}

// ---------------------------------------------------------------- finalize: + self loop + bias, relu, optional LN
__global__ void finalize_k(float* __restrict__ AGG, const float* __restrict__ H,
                           const float* __restrict__ dinv, const float* __restrict__ bias,
                           const float* __restrict__ g, const float* __restrict__ beta,
                           int doLN) {
    int tid = threadIdx.x;
    int node = blockIdx.x * 4 + (tid >> 6);
    int lane = tid & 63;
    if (node >= N_NODES) return;
    float di = dinv[node];
    long idx = (long)node * 64 + lane;
    float v = AGG[idx] + H[idx] * di * di + bias[lane];
    v = fmaxf(v, 0.f);
    if (doLN) {
        float sum = v;
        for (int off = 32; off; off >>= 1) sum += __shfl_down(sum, off);
        float mu = __shfl(sum, 0) * (1.f / 64.f);
        float dv = v - mu;
        float vs = dv * dv;
        for (int off = 32; off; off >>= 1) vs += __shfl_down(vs, off);
        float var = __shfl(vs, 0) * (1.f / 64.f);
        v = dv * rsqrtf(var + LN_EPS) * g[lane] + beta[lane];
    }
    AGG[idx] = v;
}

// ---------------------------------------------------------------- MLP head: [N,64] -> 64 -> 40
__global__ void mlp_k(const float* __restrict__ H, const float* __restrict__ W0,
                      const float* __restrict__ b0, const float* __restrict__ W1,
                      const float* __restrict__ b1, float* __restrict__ OUT) {
    __shared__ float sW0[64 * 64];
    __shared__ float sW1[64 * 40];
    __shared__ float sT[4 * 64];
    int tid = threadIdx.x;
    for (int i = tid; i < 64 * 64; i += 256) sW0[i] = W0[i];
    for (int i = tid; i < 64 * 40; i += 256) sW1[i] = W1[i];
    int w = tid >> 6, lane = tid & 63;
    int node = blockIdx.x * 4 + w;
    float hv = (node < N_NODES) ? H[(long)node * 64 + lane] : 0.f;
    __syncthreads();
    sT[w * 64 + lane] = hv;
    __syncthreads();
    float t = b0[lane];
    for (int k = 0; k < 64; ++k) t = fmaf(sT[w * 64 + k], sW0[k * 64 + lane], t);
    __syncthreads();
    sT[w * 64 + lane] = t;
    __syncthreads();
    if (node < N_NODES && lane < DOUT) {
        float o = b1[lane];
        for (int k = 0; k < 64; ++k) o = fmaf(sT[w * 64 + k], sW1[k * DOUT + lane], o);
        OUT[(long)node * DOUT + lane] = o;
    }
}

// ----------------------------------------------------------------
extern "C" void kernel_launch(void* const* d_in, const int* in_sizes, int n_in,
                              void* d_out, int out_size, void* d_ws, size_t ws_size,
                              hipStream_t stream) {
    const float* x    = (const float*)d_in[0];
    const int*   ei   = (const int*)d_in[1];          // [2,E] row-major
    const int*   srcI = ei;
    const int*   dstI = ei + E_EDGES;
    const float* W0   = (const float*)d_in[2];
    const float* b0   = (const float*)d_in[3];
    const float* W1   = (const float*)d_in[4];
    const float* b1   = (const float*)d_in[5];
    const float* W2   = (const float*)d_in[6];
    const float* b2   = (const float*)d_in[7];
    const float* ln0g = (const float*)d_in[8];
    const float* ln0b = (const float*)d_in[9];
    const float* ln1g = (const float*)d_in[10];
    const float* ln1b = (const float*)d_in[11];
    const float* mpW0 = (const float*)d_in[12];
    const float* mpb0 = (const float*)d_in[13];
    const float* mpW1 = (const float*)d_in[14];
    const float* mpb1 = (const float*)d_in[15];
    float* out = (float*)d_out;

    char* ws = (char*)d_ws;
    float* dinv = (float*)ws;                                     // N floats
    float* bufA = (float*)(ws + (1l << 20));                      // N*64 floats
    float* bufB = (float*)(ws + (1l << 20) + 27l * (1l << 20));   // N*64 floats

    const size_t hBytes = (size_t)N_NODES * 64 * sizeof(float);
    const int nodeBlocks = (N_NODES + 3) / 4;            // 25000
    const int edgeBlocks = (int)(((long)E_EDGES * 64 + 255) / 256);  // 400000

    // degrees -> dinv
    hipMemsetAsync(dinv, 0, N_NODES * sizeof(float), stream);
    deg_count_k<<<(E_EDGES + 255) / 256, 256, 0, stream>>>(dstI, dinv);
    dinv_k<<<(N_NODES + 255) / 256, 256, 0, stream>>>(dinv);

    // ---- layer 0: x [N,128] -> bufB
    gemm_nk64<128><<<nodeBlocks, 256, 0, stream>>>(x, W0, bufA);
    hipMemsetAsync(bufB, 0, hBytes, stream);
    scatter_k<<<edgeBlocks, 256, 0, stream>>>(srcI, dstI, dinv, bufA, bufB);
    finalize_k<<<nodeBlocks, 256, 0, stream>>>(bufB, bufA, dinv, b0, ln0g, ln0b, 1);

    // ---- layer 1: bufB -> bufB
    gemm_nk64<64><<<nodeBlocks, 256, 0, stream>>>(bufB, W1, bufA);
    hipMemsetAsync(bufB, 0, hBytes, stream);
    scatter_k<<<edgeBlocks, 256, 0, stream>>>(srcI, dstI, dinv, bufA, bufB);
    finalize_k<<<nodeBlocks, 256, 0, stream>>>(bufB, bufA, dinv, b1, ln1g, ln1b, 1);

    // ---- layer 2: bufB -> bufB (no LN)
    gemm_nk64<64><<<nodeBlocks, 256, 0, stream>>>(bufB, W2, bufA);
    hipMemsetAsync(bufB, 0, hBytes, stream);
    scatter_k<<<edgeBlocks, 256, 0, stream>>>(srcI, dstI, dinv, bufA, bufB);
    finalize_k<<<nodeBlocks, 256, 0, stream>>>(bufB, bufA, dinv, b2, nullptr, nullptr, 0);

    // ---- MLP head
    mlp_k<<<nodeBlocks, 256, 0, stream>>>(bufB, mpW0, mpb0, mpW1, mpb1, out);
}

// Round 2
// 1312.040 us; speedup vs baseline: 1.2421x; 1.2421x over previous
//
#include <hip/hip_runtime.h>
#include <hip/hip_bf16.h>

#define NN 100000
#define EE 1600000
#define DOUT 40
#define LN_EPS 1e-5f
#define NB 391  // (NN+255)/256

// ---------------------------------------------------------------- CSR build
__global__ void hist_k(const int* __restrict__ dst, int* __restrict__ degI) {
    int e = blockIdx.x * 256 + threadIdx.x;
    if (e < EE) atomicAdd(&degI[dst[e]], 1);
}

__global__ void dinv_k(const int* __restrict__ degI, float* __restrict__ dinv) {
    int n = blockIdx.x * 256 + threadIdx.x;
    if (n < NN) dinv[n] = rsqrtf((float)degI[n] + 1.0f);  // A + I self loop
}

// block-level exclusive scan of degI -> cursor, block totals -> bsum
__global__ void scan1_k(const int* __restrict__ degI, int* __restrict__ cursor,
                        int* __restrict__ bsum) {
    __shared__ int s[256];
    int tid = threadIdx.x;
    int i = blockIdx.x * 256 + tid;
    int v = (i < NN) ? degI[i] : 0;
    s[tid] = v;
    __syncthreads();
    for (int off = 1; off < 256; off <<= 1) {
        int t = (tid >= off) ? s[tid - off] : 0;
        __syncthreads();
        s[tid] += t;
        __syncthreads();
    }
    if (i < NN) cursor[i] = s[tid] - v;  // exclusive
    if (tid == 255) bsum[blockIdx.x] = s[255];
}

// exclusive scan of the NB block sums (NB <= 512), single block of 512
__global__ void scan2_k(int* __restrict__ bsum) {
    __shared__ int s[512];
    int tid = threadIdx.x;
    int v = (tid < NB) ? bsum[tid] : 0;
    s[tid] = v;
    __syncthreads();
    for (int off = 1; off < 512; off <<= 1) {
        int t = (tid >= off) ? s[tid - off] : 0;
        __syncthreads();
        s[tid] += t;
        __syncthreads();
    }
    if (tid < NB) bsum[tid] = s[tid] - v;
}

__global__ void scan3_k(int* __restrict__ cursor, const int* __restrict__ bsum) {
    int i = blockIdx.x * 256 + threadIdx.x;
    if (i < NN) cursor[i] += bsum[blockIdx.x];
}

// cursor holds start offsets; after this kernel cursor[n] == end offset
__global__ void reorder_k(const int* __restrict__ src, const int* __restrict__ dst,
                          int* __restrict__ cursor, int* __restrict__ csrSrc) {
    int e = blockIdx.x * 256 + threadIdx.x;
    if (e < EE) {
        int pos = atomicAdd(&cursor[dst[e]], 1);
        csrSrc[pos] = src[e];
    }
}

// ---------------------------------------------------------------- GEMM  [N,K]@[K,64] -> H' = (xW)*dinv
// grid-stride; W staged in LDS once per block; wave per node, lane = out feature.
template <int K>
__global__ void gemm_k(const float* __restrict__ X, const float* __restrict__ W,
                       const float* __restrict__ dinv, float* __restrict__ H) {
    __shared__ float sW[K * 64];
    int tid = threadIdx.x;
    for (int i = tid; i < K * 64; i += 256) sW[i] = W[i];
    __syncthreads();
    int w = tid >> 6, lane = tid & 63;
    for (int base = blockIdx.x * 4; base < NN; base += gridDim.x * 4) {
        int node = base + w;
        if (node < NN) {
            float xv[K / 64];
#pragma unroll
            for (int j = 0; j < K / 64; ++j) xv[j] = X[(long)node * K + j * 64 + lane];
            float acc = 0.f;
#pragma unroll
            for (int j = 0; j < K / 64; ++j) {
#pragma unroll
                for (int k = 0; k < 64; ++k) {
                    float xk = __shfl(xv[j], k);
                    acc = fmaf(xk, sW[(j * 64 + k) * 64 + lane], acc);
                }
            }
            H[(long)node * 64 + lane] = acc * dinv[node];
        }
    }
}

// ---------------------------------------------------------------- aggregate (pull) + bias + relu + optional LN
// wave per dst node; lane = feature.  out = dinv[d]*(sum H'[s] + H'[d]) + b
__global__ void agg_k(const int* __restrict__ cursor, const int* __restrict__ degI,
                      const int* __restrict__ csrSrc, const float* __restrict__ dinv,
                      const float* __restrict__ H, const float* __restrict__ bias,
                      const float* __restrict__ g, const float* __restrict__ beta,
                      float* __restrict__ OUT, int doLN) {
    int tid = threadIdx.x;
    int node = blockIdx.x * 4 + (tid >> 6);
    int lane = tid & 63;
    if (node >= NN) return;
    int end = cursor[node];
    int start = end - degI[node];
    float acc = 0.f;
    int sCur = (start < end) ? csrSrc[start] : 0;
    for (int e = start; e < end; ++e) {
        int sNext = (e + 1 < end) ? csrSrc[e + 1] : 0;
        acc += H[(long)sCur * 64 + lane];
        sCur = sNext;
    }
    float di = dinv[node];
    float v = (acc + H[(long)node * 64 + lane]) * di + bias[lane];
    v = fmaxf(v, 0.f);
    if (doLN) {
        float sum = v;
        for (int off = 32; off; off >>= 1) sum += __shfl_down(sum, off);
        float mu = __shfl(sum, 0) * (1.f / 64.f);
        float dv = v - mu;
        float vs = dv * dv;
        for (int off = 32; off; off >>= 1) vs += __shfl_down(vs, off);
        float var = __shfl(vs, 0) * (1.f / 64.f);
        v = dv * rsqrtf(var + LN_EPS) * g[lane] + beta[lane];
    }
    OUT[(long)node * 64 + lane] = v;
}

// ---------------------------------------------------------------- last layer: aggregate + relu + MLP head (fused)
__global__ void agg_mlp_k(const int* __restrict__ cursor, const int* __restrict__ degI,
                          const int* __restrict__ csrSrc, const float* __restrict__ dinv,
                          const float* __restrict__ H, const float* __restrict__ bias,
                          const float* __restrict__ W0, const float* __restrict__ b0,
                          const float* __restrict__ W1, const float* __restrict__ b1,
                          float* __restrict__ OUT) {
    __shared__ float sW0[64 * 64];
    __shared__ float sW1[64 * DOUT];
    int tid = threadIdx.x;
    for (int i = tid; i < 64 * 64; i += 256) sW0[i] = W0[i];
    for (int i = tid; i < 64 * DOUT; i += 256) sW1[i] = W1[i];
    __syncthreads();
    int node = blockIdx.x * 4 + (tid >> 6);
    int lane = tid & 63;
    if (node >= NN) return;
    int end = cursor[node];
    int start = end - degI[node];
    float acc = 0.f;
    int sCur = (start < end) ? csrSrc[start] : 0;
    for (int e = start; e < end; ++e) {
        int sNext = (e + 1 < end) ? csrSrc[e + 1] : 0;
        acc += H[(long)sCur * 64 + lane];
        sCur = sNext;
    }
    float di = dinv[node];
    float v = (acc + H[(long)node * 64 + lane]) * di + bias[lane];
    v = fmaxf(v, 0.f);  // conv relu (no LN on layer 2)
    // Linear 64->64 (no activation between the two head linears)
    float t = b0[lane];
#pragma unroll
    for (int k = 0; k < 64; ++k) t = fmaf(__shfl(v, k), sW0[k * 64 + lane], t);
    // Linear 64->40
    int li = (lane < DOUT) ? lane : 0;
    float o = b1[li];
#pragma unroll
    for (int k = 0; k < 64; ++k) o = fmaf(__shfl(t, k), sW1[k * DOUT + li], o);
    if (lane < DOUT) OUT[(long)node * DOUT + lane] = o;
}

// ----------------------------------------------------------------
extern "C" void kernel_launch(void* const* d_in, const int* in_sizes, int n_in,
                              void* d_out, int out_size, void* d_ws, size_t ws_size,
                              hipStream_t stream) {
    const float* x    = (const float*)d_in[0];
    const int*   ei   = (const int*)d_in[1];  // [2,E]
    const int*   srcI = ei;
    const int*   dstI = ei + EE;
    const float* W0   = (const float*)d_in[2];
    const float* b0   = (const float*)d_in[3];
    const float* W1   = (const float*)d_in[4];
    const float* b1   = (const float*)d_in[5];
    const float* W2   = (const float*)d_in[6];
    const float* b2   = (const float*)d_in[7];
    const float* ln0g = (const float*)d_in[8];
    const float* ln0b = (const float*)d_in[9];
    const float* ln1g = (const float*)d_in[10];
    const float* ln1b = (const float*)d_in[11];
    const float* mpW0 = (const float*)d_in[12];
    const float* mpb0 = (const float*)d_in[13];
    const float* mpW1 = (const float*)d_in[14];
    const float* mpb1 = (const float*)d_in[15];
    float* out = (float*)d_out;

    char* ws = (char*)d_ws;
    float* dinv   = (float*)(ws + 0);                  // N f   (400 KB)
    int*   degI   = (int*)  (ws + 512l * 1024);        // N i   (400 KB)
    int*   cursor = (int*)  (ws + 1024l * 1024);       // N i
    int*   bsum   = (int*)  (ws + 1536l * 1024);       // NB i
    int*   csrSrc = (int*)  (ws + 2048l * 1024);       // E i   (6.4 MB)
    float* bufA   = (float*)(ws + 9l * 1024 * 1024);   // N*64 f (25.6 MB)
    float* bufB   = (float*)(ws + 35l * 1024 * 1024);  // N*64 f (25.6 MB)

    const int edgeBlocks = (EE + 255) / 256;  // 6250
    const int aggBlocks  = NN / 4;            // 25000

    // ---- CSR build (by dst) + dinv
    hipMemsetAsync(degI, 0, NN * sizeof(int), stream);
    hist_k<<<edgeBlocks, 256, 0, stream>>>(dstI, degI);
    dinv_k<<<NB, 256, 0, stream>>>(degI, dinv);
    scan1_k<<<NB, 256, 0, stream>>>(degI, cursor, bsum);
    scan2_k<<<1, 512, 0, stream>>>(bsum);
    scan3_k<<<NB, 256, 0, stream>>>(cursor, bsum);
    reorder_k<<<edgeBlocks, 256, 0, stream>>>(srcI, dstI, cursor, csrSrc);

    // ---- layer 0: x [N,128] -> bufA (pre-scaled) -> agg -> bufB
    gemm_k<128><<<2048, 256, 0, stream>>>(x, W0, dinv, bufA);
    agg_k<<<aggBlocks, 256, 0, stream>>>(cursor, degI, csrSrc, dinv, bufA, b0, ln0g, ln0b, bufB, 1);

    // ---- layer 1
    gemm_k<64><<<2048, 256, 0, stream>>>(bufB, W1, dinv, bufA);
    agg_k<<<aggBlocks, 256, 0, stream>>>(cursor, degI, csrSrc, dinv, bufA, b1, ln1g, ln1b, bufB, 1);

    // ---- layer 2 + MLP head fused
    gemm_k<64><<<2048, 256, 0, stream>>>(bufB, W2, dinv, bufA);
    agg_mlp_k<<<aggBlocks, 256, 0, stream>>>(cursor, degI, csrSrc, dinv, bufA, b2,
                                             mpW0, mpb0, mpW1, mpb1, out);
}

// Round 3
// 992.466 us; speedup vs baseline: 1.6420x; 1.3220x over previous
//
#include <hip/hip_runtime.h>
#include <hip/hip_bf16.h>

#define NN 100000
#define EE 1600000
#define DOUT 40
#define LN_EPS 1e-5f
#define NB 391  // (NN+255)/256

// ---------------------------------------------------------------- CSR build
__global__ void hist_k(const int* __restrict__ dst, int* __restrict__ degI) {
    int e = blockIdx.x * 256 + threadIdx.x;
    if (e < EE) atomicAdd(&degI[dst[e]], 1);
}

__global__ void dinv_k(const int* __restrict__ degI, float* __restrict__ dinv) {
    int n = blockIdx.x * 256 + threadIdx.x;
    if (n < NN) dinv[n] = rsqrtf((float)degI[n] + 1.0f);  // A + I self loop
}

__global__ void scan1_k(const int* __restrict__ degI, int* __restrict__ cursor,
                        int* __restrict__ bsum) {
    __shared__ int s[256];
    int tid = threadIdx.x;
    int i = blockIdx.x * 256 + tid;
    int v = (i < NN) ? degI[i] : 0;
    s[tid] = v;
    __syncthreads();
    for (int off = 1; off < 256; off <<= 1) {
        int t = (tid >= off) ? s[tid - off] : 0;
        __syncthreads();
        s[tid] += t;
        __syncthreads();
    }
    if (i < NN) cursor[i] = s[tid] - v;  // exclusive
    if (tid == 255) bsum[blockIdx.x] = s[255];
}

__global__ void scan2_k(int* __restrict__ bsum) {
    __shared__ int s[512];
    int tid = threadIdx.x;
    int v = (tid < NB) ? bsum[tid] : 0;
    s[tid] = v;
    __syncthreads();
    for (int off = 1; off < 512; off <<= 1) {
        int t = (tid >= off) ? s[tid - off] : 0;
        __syncthreads();
        s[tid] += t;
        __syncthreads();
    }
    if (tid < NB) bsum[tid] = s[tid] - v;
}

__global__ void scan3_k(int* __restrict__ cursor, const int* __restrict__ bsum) {
    int i = blockIdx.x * 256 + threadIdx.x;
    if (i < NN) cursor[i] += bsum[blockIdx.x];
}

// after this kernel cursor[n] == end offset
__global__ void reorder_k(const int* __restrict__ src, const int* __restrict__ dst,
                          int* __restrict__ cursor, int* __restrict__ csrSrc) {
    int e = blockIdx.x * 256 + threadIdx.x;
    if (e < EE) {
        int pos = atomicAdd(&cursor[dst[e]], 1);
        csrSrc[pos] = src[e];
    }
}

// ---------------------------------------------------------------- GEMM  [N,K]@[K,64] -> H' = (xW)*dinv
template <int K>
__global__ void gemm_k(const float* __restrict__ X, const float* __restrict__ W,
                       const float* __restrict__ dinv, float* __restrict__ H) {
    __shared__ float sW[K * 64];
    int tid = threadIdx.x;
    for (int i = tid; i < K * 64; i += 256) sW[i] = W[i];
    __syncthreads();
    int w = tid >> 6, lane = tid & 63;
    for (int base = blockIdx.x * 4; base < NN; base += gridDim.x * 4) {
        int node = base + w;
        if (node < NN) {
            float xv[K / 64];
#pragma unroll
            for (int j = 0; j < K / 64; ++j) xv[j] = X[(long)node * K + j * 64 + lane];
            float acc = 0.f;
#pragma unroll
            for (int j = 0; j < K / 64; ++j) {
#pragma unroll
                for (int k = 0; k < 64; ++k) {
                    float xk = __shfl(xv[j], k);
                    acc = fmaf(xk, sW[(j * 64 + k) * 64 + lane], acc);
                }
            }
            H[(long)node * 64 + lane] = acc * dinv[node];
        }
    }
}

// ---------------------------------------------------------------- aggregate (pull), float4 lanes
// wave per node; 16 lanes per edge (float4 each) -> 4 edges/iter, 2-deep unroll
// => 8 gathers in flight per wave.
__device__ __forceinline__ void add4(float4& a, const float4 b) {
    a.x += b.x; a.y += b.y; a.z += b.z; a.w += b.w;
}

__global__ void agg_k(const int* __restrict__ cursor, const int* __restrict__ degI,
                      const int* __restrict__ csrSrc, const float* __restrict__ dinv,
                      const float4* __restrict__ H4, const float4* __restrict__ bias4,
                      const float4* __restrict__ g4, const float4* __restrict__ beta4,
                      float4* __restrict__ OUT4, int doLN) {
    int tid = threadIdx.x;
    int w = tid >> 6, lane = tid & 63;
    int g = lane >> 4;   // edge slot 0..3
    int f = lane & 15;   // feature-quad index
    int node = blockIdx.x * 4 + w;   // grid sized exactly: NN/4 blocks
    int end = cursor[node];
    int start = end - degI[node];
    float4 a0 = {0, 0, 0, 0}, a1 = {0, 0, 0, 0};
    int e = start + g;
    for (; e + 4 < end; e += 8) {
        int s0 = csrSrc[e];
        int s1 = csrSrc[e + 4];
        float4 v0 = H4[(long)s0 * 16 + f];
        float4 v1 = H4[(long)s1 * 16 + f];
        add4(a0, v0);
        add4(a1, v1);
    }
    if (e < end) {
        int s0 = csrSrc[e];
        add4(a0, H4[(long)s0 * 16 + f]);
    }
    add4(a0, a1);
    // reduce the 4 edge slots: every lane ends with the full edge sum
    a0.x += __shfl_xor(a0.x, 16); a0.y += __shfl_xor(a0.y, 16);
    a0.z += __shfl_xor(a0.z, 16); a0.w += __shfl_xor(a0.w, 16);
    a0.x += __shfl_xor(a0.x, 32); a0.y += __shfl_xor(a0.y, 32);
    a0.z += __shfl_xor(a0.z, 32); a0.w += __shfl_xor(a0.w, 32);
    float di = dinv[node];
    float4 self = H4[(long)node * 16 + f];
    float4 b = bias4[f];
    float4 v;
    v.x = fmaxf((a0.x + self.x) * di + b.x, 0.f);
    v.y = fmaxf((a0.y + self.y) * di + b.y, 0.f);
    v.z = fmaxf((a0.z + self.z) * di + b.z, 0.f);
    v.w = fmaxf((a0.w + self.w) * di + b.w, 0.f);
    if (doLN) {
        float s = v.x + v.y + v.z + v.w;
        for (int m = 1; m < 16; m <<= 1) s += __shfl_xor(s, m);
        float mu = s * (1.f / 64.f);
        float dx = v.x - mu, dy = v.y - mu, dz = v.z - mu, dw = v.w - mu;
        float vs = dx * dx + dy * dy + dz * dz + dw * dw;
        for (int m = 1; m < 16; m <<= 1) vs += __shfl_xor(vs, m);
        float inv = rsqrtf(vs * (1.f / 64.f) + LN_EPS);
        float4 G = g4[f], B = beta4[f];
        v.x = dx * inv * G.x + B.x;
        v.y = dy * inv * G.y + B.y;
        v.z = dz * inv * G.z + B.z;
        v.w = dw * inv * G.w + B.w;
    }
    if (g == 0) OUT4[(long)node * 16 + f] = v;
}

// ---------------------------------------------------------------- last layer: aggregate + relu + MLP head
__global__ void agg_mlp_k(const int* __restrict__ cursor, const int* __restrict__ degI,
                          const int* __restrict__ csrSrc, const float* __restrict__ dinv,
                          const float4* __restrict__ H4, const float4* __restrict__ bias4,
                          const float* __restrict__ W0, const float* __restrict__ b0,
                          const float* __restrict__ W1, const float* __restrict__ b1,
                          float* __restrict__ OUT) {
    __shared__ float sW0[64 * 64];
    __shared__ float sW1[64 * DOUT];
    __shared__ float sT[4 * 64];
    int tid = threadIdx.x;
    for (int i = tid; i < 64 * 64; i += 256) sW0[i] = W0[i];
    for (int i = tid; i < 64 * DOUT; i += 256) sW1[i] = W1[i];
    __syncthreads();
    int w = tid >> 6, lane = tid & 63;
    int g = lane >> 4, f = lane & 15;
    int node = blockIdx.x * 4 + w;
    int end = cursor[node];
    int start = end - degI[node];
    float4 a0 = {0, 0, 0, 0}, a1 = {0, 0, 0, 0};
    int e = start + g;
    for (; e + 4 < end; e += 8) {
        int s0 = csrSrc[e];
        int s1 = csrSrc[e + 4];
        float4 v0 = H4[(long)s0 * 16 + f];
        float4 v1 = H4[(long)s1 * 16 + f];
        add4(a0, v0);
        add4(a1, v1);
    }
    if (e < end) {
        int s0 = csrSrc[e];
        add4(a0, H4[(long)s0 * 16 + f]);
    }
    add4(a0, a1);
    a0.x += __shfl_xor(a0.x, 16); a0.y += __shfl_xor(a0.y, 16);
    a0.z += __shfl_xor(a0.z, 16); a0.w += __shfl_xor(a0.w, 16);
    a0.x += __shfl_xor(a0.x, 32); a0.y += __shfl_xor(a0.y, 32);
    a0.z += __shfl_xor(a0.z, 32); a0.w += __shfl_xor(a0.w, 32);
    float di = dinv[node];
    float4 self = H4[(long)node * 16 + f];
    float4 b = bias4[f];
    float4 v;
    v.x = fmaxf((a0.x + self.x) * di + b.x, 0.f);
    v.y = fmaxf((a0.y + self.y) * di + b.y, 0.f);
    v.z = fmaxf((a0.z + self.z) * di + b.z, 0.f);
    v.w = fmaxf((a0.w + self.w) * di + b.w, 0.f);
    // stage to per-wave LDS slot (intra-wave, lockstep: no barrier needed)
    if (g == 0) ((float4*)sT)[w * 16 + f] = v;
    float hv = sT[w * 64 + lane];  // lane = feature
    // Linear 64->64
    float t = b0[lane];
#pragma unroll
    for (int k = 0; k < 64; ++k) t = fmaf(sT[w * 64 + k], sW0[k * 64 + lane], t);
    // Linear 64->40
    (void)hv;
    int li = (lane < DOUT) ? lane : 0;
    float o = b1[li];
#pragma unroll
    for (int k = 0; k < 64; ++k) o = fmaf(__shfl(t, k), sW1[k * DOUT + li], o);
    if (lane < DOUT) OUT[(long)node * DOUT + lane] = o;
}

// ----------------------------------------------------------------
extern "C" void kernel_launch(void* const* d_in, const int* in_sizes, int n_in,
                              void* d_out, int out_size, void* d_ws, size_t ws_size,
                              hipStream_t stream) {
    const float* x    = (const float*)d_in[0];
    const int*   ei   = (const int*)d_in[1];  // [2,E]
    const int*   srcI = ei;
    const int*   dstI = ei + EE;
    const float* W0   = (const float*)d_in[2];
    const float* b0   = (const float*)d_in[3];
    const float* W1   = (const float*)d_in[4];
    const float* b1   = (const float*)d_in[5];
    const float* W2   = (const float*)d_in[6];
    const float* b2   = (const float*)d_in[7];
    const float* ln0g = (const float*)d_in[8];
    const float* ln0b = (const float*)d_in[9];
    const float* ln1g = (const float*)d_in[10];
    const float* ln1b = (const float*)d_in[11];
    const float* mpW0 = (const float*)d_in[12];
    const float* mpb0 = (const float*)d_in[13];
    const float* mpW1 = (const float*)d_in[14];
    const float* mpb1 = (const float*)d_in[15];
    float* out = (float*)d_out;

    char* ws = (char*)d_ws;
    float* dinv   = (float*)(ws + 0);
    int*   degI   = (int*)  (ws + 512l * 1024);
    int*   cursor = (int*)  (ws + 1024l * 1024);
    int*   bsum   = (int*)  (ws + 1536l * 1024);
    int*   csrSrc = (int*)  (ws + 2048l * 1024);
    float* bufA   = (float*)(ws + 9l * 1024 * 1024);
    float* bufB   = (float*)(ws + 35l * 1024 * 1024);

    const int edgeBlocks = (EE + 255) / 256;  // 6250
    const int aggBlocks  = NN / 4;            // 25000 (exact)

    hipMemsetAsync(degI, 0, NN * sizeof(int), stream);
    hist_k<<<edgeBlocks, 256, 0, stream>>>(dstI, degI);
    dinv_k<<<NB, 256, 0, stream>>>(degI, dinv);
    scan1_k<<<NB, 256, 0, stream>>>(degI, cursor, bsum);
    scan2_k<<<1, 512, 0, stream>>>(bsum);
    scan3_k<<<NB, 256, 0, stream>>>(cursor, bsum);
    reorder_k<<<edgeBlocks, 256, 0, stream>>>(srcI, dstI, cursor, csrSrc);

    // layer 0
    gemm_k<128><<<2048, 256, 0, stream>>>(x, W0, dinv, bufA);
    agg_k<<<aggBlocks, 256, 0, stream>>>(cursor, degI, csrSrc, dinv, (const float4*)bufA,
                                         (const float4*)b0, (const float4*)ln0g,
                                         (const float4*)ln0b, (float4*)bufB, 1);
    // layer 1
    gemm_k<64><<<2048, 256, 0, stream>>>(bufB, W1, dinv, bufA);
    agg_k<<<aggBlocks, 256, 0, stream>>>(cursor, degI, csrSrc, dinv, (const float4*)bufA,
                                         (const float4*)b1, (const float4*)ln1g,
                                         (const float4*)ln1b, (float4*)bufB, 1);
    // layer 2 + MLP head
    gemm_k<64><<<2048, 256, 0, stream>>>(bufB, W2, dinv, bufA);
    agg_mlp_k<<<aggBlocks, 256, 0, stream>>>(cursor, degI, csrSrc, dinv, (const float4*)bufA,
                                             (const float4*)b2, mpW0, mpb0, mpW1, mpb1, out);
}